// Round 8
// baseline (36.253 us; speedup 1.0000x reference)
//
#include <hip/hip_runtime.h>
#include <stdint.h>

// Dilated attention, collapsed form.
// q,k,v: [B=4, D=256, N=8192] f32 (n contiguous). out: [B, N, D] f32.
// HEAD_DIM=32, heads H=8, taps {-2,0,+2} along n, 6 zero-pad softmax slots.
//
// R8: async LDS staging. R4/R5/R7 all plateau at ~40us cold / ~30us bench
// (2.4-2.8 TB/s) across wildly different occupancy & instruction mixes ->
// consume-immediately load structure caps loads-in-flight (latency-bound).
// Fix: fire-and-forget global_load_lds (width 16) stages K,V tiles
// [32ch][128n] (16KB each, rows linear so each 1KB wave-instr = 2 rows)
// plus 1KB edge-clamped halo strips; taps then come from LDS. q stays in
// registers (read-once). Same math/reduce/store path as R7.
// History: R1 43us; R2 spill 105us; R3 59us; R4 41us; R5 41us(WRITE 54MB);
// R7 39.7us cold / 29.3us bench (WRITE fixed).

constexpr int Bn = 4;
constexpr int Dd = 256;
constexpr int Nn = 8192;
constexpr int HD = 32;
constexpr int Hh = Dd / HD;          // 8
constexpr int NT = 128;              // n per block
constexpr int THREADS = 128;         // 2 waves
constexpr float SCALE = 0.17677669529663687f;  // 32^-0.5

typedef float vfloat4 __attribute__((ext_vector_type(4)));

__device__ __forceinline__ void gload_lds16(const float* g, float* l) {
    // width=16: global_load_lds_dwordx4; LDS dest = uniform base + lane*16.
    __builtin_amdgcn_global_load_lds(
        (const __attribute__((address_space(1))) void*)g,
        (__attribute__((address_space(3))) void*)l, 16, 0, 0);
}

__global__ __launch_bounds__(THREADS) void dilate_attn_kernel(
    const float* __restrict__ q,
    const float* __restrict__ k,
    const float* __restrict__ v,
    float* __restrict__ out)
{
    __shared__ float kt[32 * NT];     // 16 KB, row = channel, 512 B rows
    __shared__ float vt[32 * NT];     // 16 KB
    __shared__ float khalo[32 * 8];   // 1 KB: [ch][0..3]=n0-4.. , [4..7]=n0+128..
    __shared__ float vhalo[32 * 8];   // 1 KB

    const int tid     = threadIdx.x;
    const int w       = tid >> 6;         // wave (0..1)
    const int lane    = tid & 63;
    const int quarter = lane >> 4;        // channel octet (0..3)
    const int sub     = w * 16 + (lane & 15);   // n-quad (0..31)

    const int blk   = blockIdx.x;         // 2048 blocks
    const int bh    = blk >> 6;           // 64 blocks per (b,h)
    const int blkn  = blk & 63;
    const int h     = bh & (Hh - 1);
    const int b     = bh >> 3;
    const int nstart  = blkn * NT;
    const int base_bh = (b * Dd + h * HD) * Nn;   // first of the 32 rows

    // ---- stage K,V tiles + halos (fire-and-forget) ----
    {
        const int l31   = lane & 31;
        const int rhalf = lane >> 5;
        #pragma unroll
        for (int i8 = 0; i8 < 8; ++i8) {
            const int i   = w * 8 + i8;           // instr 0..15
            const int row = 2 * i + rhalf;        // each 1KB instr = rows 2i,2i+1
            gload_lds16(k + base_bh + row * Nn + nstart + l31 * 4, &kt[i * 256]);
        }
        #pragma unroll
        for (int i8 = 0; i8 < 8; ++i8) {
            const int i   = w * 8 + i8;
            const int row = 2 * i + rhalf;
            gload_lds16(v + base_bh + row * Nn + nstart + l31 * 4, &vt[i * 256]);
        }
        // halo strip: lane l -> ch = l>>1, half = l&1; 4 floats each side.
        const int hch  = lane >> 1;
        const int half = lane & 1;
        int gcol = nstart + (half ? NT : -4);
        gcol = gcol < 0 ? 0 : (gcol > Nn - 4 ? Nn - 4 : gcol);  // clamp; masked later
        if (w == 0) gload_lds16(k + base_bh + hch * Nn + gcol, &khalo[0]);
        else        gload_lds16(v + base_bh + hch * Nn + gcol, &vhalo[0]);
    }

    // ---- q into registers (read-once), overlaps staging ----
    const int n0l = sub * 4;              // local n (0..124)
    const int n0  = nstart + n0l;         // global n
    float4 qc[8];
    const float* qb = q + base_bh + (quarter * 8) * Nn + nstart + n0l;
    #pragma unroll
    for (int c = 0; c < 8; ++c)
        qc[c] = *reinterpret_cast<const float4*>(qb + c * Nn);

    __syncthreads();                      // drains vmcnt: staging complete

    const bool hasL = (n0 >= 2);
    const bool hasR = (n0 + 4 < Nn);

    // ---- phase 1: logits for rows n0..n0+3 over this octet's 8 channels ----
    // taps per row j: j0: km.x kc.x kc.z | j1: km.y kc.y kc.w
    //                 j2: kc.x kc.z kp.x | j3: kc.y kc.w kp.y
    float s0[4] = {0.f, 0.f, 0.f, 0.f};
    float s1[4] = {0.f, 0.f, 0.f, 0.f};
    float s2[4] = {0.f, 0.f, 0.f, 0.f};
    #pragma unroll
    for (int c = 0; c < 8; ++c) {
        const int row = quarter * 8 + c;
        const float4 kc = *reinterpret_cast<const float4*>(&kt[row * NT + n0l]);
        const float* pm = (sub == 0)  ? &khalo[row * 8 + 2] : &kt[row * NT + n0l - 2];
        const float* pp = (sub == 31) ? &khalo[row * 8 + 4] : &kt[row * NT + n0l + 4];
        const float2 kmr = *reinterpret_cast<const float2*>(pm);
        const float2 kpr = *reinterpret_cast<const float2*>(pp);
        const float2 km = hasL ? kmr : make_float2(0.f, 0.f);
        const float2 kp = hasR ? kpr : make_float2(0.f, 0.f);
        s0[0] = fmaf(qc[c].x, km.x, s0[0]);
        s1[0] = fmaf(qc[c].x, kc.x, s1[0]);
        s2[0] = fmaf(qc[c].x, kc.z, s2[0]);
        s0[1] = fmaf(qc[c].y, km.y, s0[1]);
        s1[1] = fmaf(qc[c].y, kc.y, s1[1]);
        s2[1] = fmaf(qc[c].y, kc.w, s2[1]);
        s0[2] = fmaf(qc[c].z, kc.x, s0[2]);
        s1[2] = fmaf(qc[c].z, kc.z, s1[2]);
        s2[2] = fmaf(qc[c].z, kp.x, s2[2]);
        s0[3] = fmaf(qc[c].w, kc.y, s0[3]);
        s1[3] = fmaf(qc[c].w, kc.w, s1[3]);
        s2[3] = fmaf(qc[c].w, kp.y, s2[3]);
    }

    // reduce across the 4 channel-quarters; softmax per row (+6 zero pads)
    float p0[4], p1[4], p2[4];
    #pragma unroll
    for (int j = 0; j < 4; ++j) {
        float a = s0[j], bb = s1[j], cc = s2[j];
        a  += __shfl_xor(a, 16, 64);  a  += __shfl_xor(a, 32, 64);
        bb += __shfl_xor(bb, 16, 64); bb += __shfl_xor(bb, 32, 64);
        cc += __shfl_xor(cc, 16, 64); cc += __shfl_xor(cc, 32, 64);
        a *= SCALE; bb *= SCALE; cc *= SCALE;
        const float m  = fmaxf(fmaxf(a, bb), fmaxf(cc, 0.f));
        const float e0 = __expf(a - m);
        const float e1 = __expf(bb - m);
        const float e2 = __expf(cc - m);
        const float inv = 1.f / (e0 + e1 + e2 + 6.f * __expf(-m));
        p0[j] = e0 * inv; p1[j] = e1 * inv; p2[j] = e2 * inv;
    }

    // ---- phase 3: PV from LDS over all 8 channels, then 32 B/row stores ----
    float t[4][8];
    #pragma unroll
    for (int c = 0; c < 8; ++c) {
        const int row = quarter * 8 + c;
        const float4 vc = *reinterpret_cast<const float4*>(&vt[row * NT + n0l]);
        const float* pm = (sub == 0)  ? &vhalo[row * 8 + 2] : &vt[row * NT + n0l - 2];
        const float* pp = (sub == 31) ? &vhalo[row * 8 + 4] : &vt[row * NT + n0l + 4];
        const float2 vmr = *reinterpret_cast<const float2*>(pm);
        const float2 vpr = *reinterpret_cast<const float2*>(pp);
        const float2 vm = hasL ? vmr : make_float2(0.f, 0.f);
        const float2 vp = hasR ? vpr : make_float2(0.f, 0.f);
        t[0][c] = fmaf(p0[0], vm.x, fmaf(p1[0], vc.x, p2[0] * vc.z));
        t[1][c] = fmaf(p0[1], vm.y, fmaf(p1[1], vc.y, p2[1] * vc.w));
        t[2][c] = fmaf(p0[2], vc.x, fmaf(p1[2], vc.z, p2[2] * vp.x));
        t[3][c] = fmaf(p0[3], vc.y, fmaf(p1[3], vc.w, p2[3] * vp.y));
    }

    // out[b][n0+j][h*32 + quarter*8 .. +7]: back-to-back nontemporal stores;
    // the wave's 4 quarters tile complete 128 B row chunks.
    float* ob = out + (b * Nn + n0) * Dd + h * HD + quarter * 8;
    #pragma unroll
    for (int j = 0; j < 4; ++j) {
        vfloat4* p = reinterpret_cast<vfloat4*>(ob + j * Dd);
        vfloat4 a0 = {t[j][0], t[j][1], t[j][2], t[j][3]};
        vfloat4 a1 = {t[j][4], t[j][5], t[j][6], t[j][7]};
        __builtin_nontemporal_store(a0, p);
        __builtin_nontemporal_store(a1, p + 1);
    }
}

extern "C" void kernel_launch(void* const* d_in, const int* in_sizes, int n_in,
                              void* d_out, int out_size, void* d_ws, size_t ws_size,
                              hipStream_t stream)
{
    const float* q = (const float*)d_in[0];
    const float* k = (const float*)d_in[1];
    const float* v = (const float*)d_in[2];
    float* out = (float*)d_out;

    const int blocks = Bn * Hh * (Nn / NT);    // 2048
    dilate_attn_kernel<<<blocks, THREADS, 0, stream>>>(q, k, v, out);
}

// Round 9
// 29.644 us; speedup vs baseline: 1.2229x; 1.2229x over previous
//
#include <hip/hip_runtime.h>

// Dilated attention, collapsed form.
// q,k,v: [B=4, D=256, N=8192] f32 (n contiguous). out: [B, N, D] f32.
// HEAD_DIM=32, heads H=8, taps {-2,0,+2} along n, 6 zero-pad softmax slots.
//
// R9: occupancy x fat-loads. R4(58%occ,scalar)/R7(25%occ,float4)/R8(LDS)
// all ~40us cold -> in-flight-bytes/CU roughly constant. This round: thread
// = 4 n x 4 channels (loads/thread 56->28, VGPR target <=64), grid 2x ->
// 8192 waves = 32/CU, so high occupancy AND 16B loads together. Reduce
// across 8 channel-groups via shfl_xor(8|16|32). R7's exact f2 halos and
// back-to-back nontemporal 16B stores retained (wave's 8 cgs tile 128 B/row).
// History: R1 43; R2 spill 105; R3 59; R4 41; R5 41; R7 29.3 bench/39.7 cold;
// R8 LDS regress 36.3 (halo line-fetch +8MB, 4-way bank conflict, 15% occ).

constexpr int Bn = 4;
constexpr int Dd = 256;
constexpr int Nn = 8192;
constexpr int HD = 32;
constexpr int Hh = Dd / HD;          // 8
constexpr float SCALE = 0.17677669529663687f;  // 32^-0.5

typedef float vfloat4 __attribute__((ext_vector_type(4)));

__global__ __launch_bounds__(256) void dilate_attn_kernel(
    const float* __restrict__ q,
    const float* __restrict__ k,
    const float* __restrict__ v,
    float* __restrict__ out)
{
    const int tid  = threadIdx.x;
    const int lane = tid & 63;
    const int subq = lane & 7;            // n-quad within wave (0..7)
    const int cg   = lane >> 3;           // channel group of 4 (0..7)
    const int w    = tid >> 6;            // wave in block (0..3)

    const int blk  = blockIdx.x;          // 2048 blocks
    const int bh   = blk >> 6;            // 64 blocks per (b,h)
    const int h    = bh & (Hh - 1);
    const int b    = bh >> 3;
    // block covers 128 n: 4 waves x 8 quads x 4 n
    const int n0 = ((blk & 63) << 7) + (w << 5) + (subq << 2);

    const int cb = (b * Dd + h * HD + cg * 4) * Nn + n0;   // fits in int
    const float* qb = q + cb;
    const float* kb = k + cb;
    const float* vb = v + cb;

    const bool hasL = (n0 >= 4);          // f2 at n0-2 fully in-bounds
    const bool hasR = (n0 + 4 < Nn);      // f2 at n0+4 fully in-bounds

    // ---- phase 1: partial logits for rows n0..n0+3 over 4 channels ----
    // taps per row j (k[n0+j-2], k[n0+j], k[n0+j+2]):
    //  j=0: km.x kc.x kc.z | j=1: km.y kc.y kc.w
    //  j=2: kc.x kc.z kp.x | j=3: kc.y kc.w kp.y
    float s0[4] = {0.f, 0.f, 0.f, 0.f};
    float s1[4] = {0.f, 0.f, 0.f, 0.f};
    float s2[4] = {0.f, 0.f, 0.f, 0.f};
    #pragma unroll
    for (int c = 0; c < 4; ++c) {
        const int o = c * Nn;             // uniform -> SGPR base step
        const float4 qc = *reinterpret_cast<const float4*>(qb + o);
        const float4 kc = *reinterpret_cast<const float4*>(kb + o);
        float2 km = make_float2(0.f, 0.f), kp = make_float2(0.f, 0.f);
        if (hasL) km = *reinterpret_cast<const float2*>(kb + o - 2);
        if (hasR) kp = *reinterpret_cast<const float2*>(kb + o + 4);
        s0[0] = fmaf(qc.x, km.x, s0[0]);
        s1[0] = fmaf(qc.x, kc.x, s1[0]);
        s2[0] = fmaf(qc.x, kc.z, s2[0]);
        s0[1] = fmaf(qc.y, km.y, s0[1]);
        s1[1] = fmaf(qc.y, kc.y, s1[1]);
        s2[1] = fmaf(qc.y, kc.w, s2[1]);
        s0[2] = fmaf(qc.z, kc.x, s0[2]);
        s1[2] = fmaf(qc.z, kc.z, s1[2]);
        s2[2] = fmaf(qc.z, kp.x, s2[2]);
        s0[3] = fmaf(qc.w, kc.y, s0[3]);
        s1[3] = fmaf(qc.w, kc.w, s1[3]);
        s2[3] = fmaf(qc.w, kp.y, s2[3]);
    }

    // reduce across the 8 channel-groups (lane bits 3,4,5); softmax per row
    float p0[4], p1[4], p2[4];
    #pragma unroll
    for (int j = 0; j < 4; ++j) {
        float a = s0[j], bb = s1[j], cc = s2[j];
        a  += __shfl_xor(a,  8, 64); a  += __shfl_xor(a, 16, 64); a  += __shfl_xor(a, 32, 64);
        bb += __shfl_xor(bb, 8, 64); bb += __shfl_xor(bb, 16, 64); bb += __shfl_xor(bb, 32, 64);
        cc += __shfl_xor(cc, 8, 64); cc += __shfl_xor(cc, 16, 64); cc += __shfl_xor(cc, 32, 64);
        a *= SCALE; bb *= SCALE; cc *= SCALE;
        const float m  = fmaxf(fmaxf(a, bb), fmaxf(cc, 0.f));
        const float e0 = __expf(a - m);
        const float e1 = __expf(bb - m);
        const float e2 = __expf(cc - m);
        const float inv = 1.f / (e0 + e1 + e2 + 6.f * __expf(-m));
        p0[j] = e0 * inv; p1[j] = e1 * inv; p2[j] = e2 * inv;
    }

    // ---- phase 3: PV over 4 channels, then one 16 B store per row ----
    float t[4][4];                        // [row j][channel c]
    #pragma unroll
    for (int c = 0; c < 4; ++c) {
        const int o = c * Nn;
        const float4 vc = *reinterpret_cast<const float4*>(vb + o);
        float2 vm = make_float2(0.f, 0.f), vp = make_float2(0.f, 0.f);
        if (hasL) vm = *reinterpret_cast<const float2*>(vb + o - 2);
        if (hasR) vp = *reinterpret_cast<const float2*>(vb + o + 4);
        t[0][c] = fmaf(p0[0], vm.x, fmaf(p1[0], vc.x, p2[0] * vc.z));
        t[1][c] = fmaf(p0[1], vm.y, fmaf(p1[1], vc.y, p2[1] * vc.w));
        t[2][c] = fmaf(p0[2], vc.x, fmaf(p1[2], vc.z, p2[2] * vp.x));
        t[3][c] = fmaf(p0[3], vc.y, fmaf(p1[3], vc.w, p2[3] * vp.y));
    }

    // out[b][n0+j][h*32 + cg*4 .. +3]: 16 B per lane per row; the wave's
    // 8 channel-groups tile complete 128 B row chunks. Nontemporal: output
    // is write-once, keep it out of L2.
    float* ob = out + (b * Nn + n0) * Dd + h * HD + cg * 4;
    #pragma unroll
    for (int j = 0; j < 4; ++j) {
        vfloat4 a = {t[j][0], t[j][1], t[j][2], t[j][3]};
        __builtin_nontemporal_store(a, reinterpret_cast<vfloat4*>(ob + j * Dd));
    }
}

extern "C" void kernel_launch(void* const* d_in, const int* in_sizes, int n_in,
                              void* d_out, int out_size, void* d_ws, size_t ws_size,
                              hipStream_t stream)
{
    const float* q = (const float*)d_in[0];
    const float* k = (const float*)d_in[1];
    const float* v = (const float*)d_in[2];
    float* out = (float*)d_out;

    // B*H*(N/4) quads x 8 channel-groups = 524288 threads
    const int total_threads = Bn * Hh * (Nn / 4) * 8;
    dilate_attn_kernel<<<total_threads / 256, 256, 0, stream>>>(q, k, v, out);
}

// Round 10
// 26.293 us; speedup vs baseline: 1.3788x; 1.1274x over previous
//
#include <hip/hip_runtime.h>

// Dilated attention, collapsed form.
// q,k,v: [B=4, D=256, N=8192] f32 (n contiguous). out: [B, N, D] f32.
// HEAD_DIM=32, heads H=8, taps {-2,0,+2} along n, 6 zero-pad softmax slots.
//
// R10: single-latency-exposure. R4/R7/R9 (different occupancy & widths) all
// ~29.5us bench -> not occupancy, not load width. Shared flaw: v-loads are
// issued only AFTER reduce+softmax -> two full memory-latency exposures per
// thread. Now ALL loads (q, k+halos, v+halos; 28 instrs) issue back-to-back
// up-front; vmcnt retires in-order so k is consumable while v is in flight,
// and v arrives during reduce/softmax for free. ~110 VGPR / 4 waves per SIMD
// is fine (wave count 16 vs 32 per CU made no difference R7 vs R9).
// Plus XCD-chunk swizzle: orig=(bid&7)*256+(bid>>3) keeps each (b,h)'s
// streams on one XCD's L2.
// History: R1 43; R2 spill 105; R3 59; R4 41/34b; R5 41; R7 39.7/29.3b;
// R8 LDS regress 36.3b; R9 29.6b (occupancy x fat-loads: neutral).

constexpr int Bn = 4;
constexpr int Dd = 256;
constexpr int Nn = 8192;
constexpr int HD = 32;
constexpr int Hh = Dd / HD;          // 8
constexpr float SCALE = 0.17677669529663687f;  // 32^-0.5

typedef float vfloat4 __attribute__((ext_vector_type(4)));

__global__ __launch_bounds__(256) void dilate_attn_kernel(
    const float* __restrict__ q,
    const float* __restrict__ k,
    const float* __restrict__ v,
    float* __restrict__ out)
{
    const int tid  = threadIdx.x;
    const int lane = tid & 63;
    const int subq = lane & 7;            // n-quad within wave (0..7)
    const int cg   = lane >> 3;           // channel group of 4 (0..7)
    const int w    = tid >> 6;            // wave in block (0..3)

    // XCD-chunk swizzle: dispatch i lands on XCD i%8; give XCD x the
    // contiguous orig-chunk [x*256, (x+1)*256).
    const int orig = ((blockIdx.x & 7) << 8) + (blockIdx.x >> 3);   // 2048 blocks
    const int bh   = orig >> 6;           // 64 blocks per (b,h)
    const int h    = bh & (Hh - 1);
    const int b    = bh >> 3;
    // block covers 128 n: 4 waves x 8 quads x 4 n
    const int n0 = ((orig & 63) << 7) + (w << 5) + (subq << 2);

    const int cb = (b * Dd + h * HD + cg * 4) * Nn + n0;   // fits in int
    const float* qb = q + cb;
    const float* kb = k + cb;
    const float* vb = v + cb;

    const bool hasL = (n0 >= 4);          // f2 at n0-2 fully in-bounds (n0==0 only fail)
    const bool hasR = (n0 + 4 < Nn);      // f2 at n0+4 fully in-bounds

    // ---- issue ALL loads up-front, back-to-back: q, k(+halo), v(+halo) ----
    float4 qv[4], kc4[4], vc4[4];
    float2 km2[4], kp2[4], vm2[4], vp2[4];
    #pragma unroll
    for (int c = 0; c < 4; ++c) {
        const int o = c * Nn;             // uniform -> SGPR base step
        qv[c] = *reinterpret_cast<const float4*>(qb + o);
    }
    #pragma unroll
    for (int c = 0; c < 4; ++c) {
        const int o = c * Nn;
        kc4[c] = *reinterpret_cast<const float4*>(kb + o);
        km2[c] = hasL ? *reinterpret_cast<const float2*>(kb + o - 2) : make_float2(0.f, 0.f);
        kp2[c] = hasR ? *reinterpret_cast<const float2*>(kb + o + 4) : make_float2(0.f, 0.f);
    }
    #pragma unroll
    for (int c = 0; c < 4; ++c) {
        const int o = c * Nn;
        vc4[c] = *reinterpret_cast<const float4*>(vb + o);
        vm2[c] = hasL ? *reinterpret_cast<const float2*>(vb + o - 2) : make_float2(0.f, 0.f);
        vp2[c] = hasR ? *reinterpret_cast<const float2*>(vb + o + 4) : make_float2(0.f, 0.f);
    }

    // ---- phase 1: partial logits for rows n0..n0+3 over 4 channels ----
    // taps per row j (k[n0+j-2], k[n0+j], k[n0+j+2]):
    //  j=0: km.x kc.x kc.z | j=1: km.y kc.y kc.w
    //  j=2: kc.x kc.z kp.x | j=3: kc.y kc.w kp.y
    float s0[4] = {0.f, 0.f, 0.f, 0.f};
    float s1[4] = {0.f, 0.f, 0.f, 0.f};
    float s2[4] = {0.f, 0.f, 0.f, 0.f};
    #pragma unroll
    for (int c = 0; c < 4; ++c) {
        const float4 qc = qv[c];
        const float4 kc = kc4[c];
        const float2 km = km2[c];
        const float2 kp = kp2[c];
        s0[0] = fmaf(qc.x, km.x, s0[0]);
        s1[0] = fmaf(qc.x, kc.x, s1[0]);
        s2[0] = fmaf(qc.x, kc.z, s2[0]);
        s0[1] = fmaf(qc.y, km.y, s0[1]);
        s1[1] = fmaf(qc.y, kc.y, s1[1]);
        s2[1] = fmaf(qc.y, kc.w, s2[1]);
        s0[2] = fmaf(qc.z, kc.x, s0[2]);
        s1[2] = fmaf(qc.z, kc.z, s1[2]);
        s2[2] = fmaf(qc.z, kp.x, s2[2]);
        s0[3] = fmaf(qc.w, kc.y, s0[3]);
        s1[3] = fmaf(qc.w, kc.w, s1[3]);
        s2[3] = fmaf(qc.w, kp.y, s2[3]);
    }

    // reduce across the 8 channel-groups (lane bits 3,4,5); softmax per row.
    // v-loads are completing in the background during this whole phase.
    float p0[4], p1[4], p2[4];
    #pragma unroll
    for (int j = 0; j < 4; ++j) {
        float a = s0[j], bb = s1[j], cc = s2[j];
        a  += __shfl_xor(a,  8, 64); a  += __shfl_xor(a, 16, 64); a  += __shfl_xor(a, 32, 64);
        bb += __shfl_xor(bb, 8, 64); bb += __shfl_xor(bb, 16, 64); bb += __shfl_xor(bb, 32, 64);
        cc += __shfl_xor(cc, 8, 64); cc += __shfl_xor(cc, 16, 64); cc += __shfl_xor(cc, 32, 64);
        a *= SCALE; bb *= SCALE; cc *= SCALE;
        const float m  = fmaxf(fmaxf(a, bb), fmaxf(cc, 0.f));
        const float e0 = __expf(a - m);
        const float e1 = __expf(bb - m);
        const float e2 = __expf(cc - m);
        const float inv = 1.f / (e0 + e1 + e2 + 6.f * __expf(-m));
        p0[j] = e0 * inv; p1[j] = e1 * inv; p2[j] = e2 * inv;
    }

    // ---- phase 3: PV over 4 channels (v already resident), 16 B store/row ----
    float t[4][4];                        // [row j][channel c]
    #pragma unroll
    for (int c = 0; c < 4; ++c) {
        const float4 vc = vc4[c];
        const float2 vm = vm2[c];
        const float2 vp = vp2[c];
        t[0][c] = fmaf(p0[0], vm.x, fmaf(p1[0], vc.x, p2[0] * vc.z));
        t[1][c] = fmaf(p0[1], vm.y, fmaf(p1[1], vc.y, p2[1] * vc.w));
        t[2][c] = fmaf(p0[2], vc.x, fmaf(p1[2], vc.z, p2[2] * vp.x));
        t[3][c] = fmaf(p0[3], vc.y, fmaf(p1[3], vc.w, p2[3] * vp.y));
    }

    // out[b][n0+j][h*32 + cg*4 .. +3]: 16 B per lane per row; the wave's
    // 8 channel-groups tile complete 128 B row chunks. Nontemporal: output
    // is write-once, keep it out of L2.
    float* ob = out + (b * Nn + n0) * Dd + h * HD + cg * 4;
    #pragma unroll
    for (int j = 0; j < 4; ++j) {
        vfloat4 a = {t[j][0], t[j][1], t[j][2], t[j][3]};
        __builtin_nontemporal_store(a, reinterpret_cast<vfloat4*>(ob + j * Dd));
    }
}

extern "C" void kernel_launch(void* const* d_in, const int* in_sizes, int n_in,
                              void* d_out, int out_size, void* d_ws, size_t ws_size,
                              hipStream_t stream)
{
    const float* q = (const float*)d_in[0];
    const float* k = (const float*)d_in[1];
    const float* v = (const float*)d_in[2];
    float* out = (float*)d_out;

    // B*H*(N/4) quads x 8 channel-groups = 524288 threads = 2048 blocks
    const int total_threads = Bn * Hh * (Nn / 4) * 8;
    dilate_attn_kernel<<<total_threads / 256, 256, 0, stream>>>(q, k, v, out);
}